// Round 10
// baseline (374.971 us; speedup 1.0000x reference)
//
#include <hip/hip_runtime.h>
#include <math.h>

#define DD   72
#define MID  36
#define NBLK 16

typedef _Float16 half8 __attribute__((ext_vector_type(8)));
typedef _Float16 half4 __attribute__((ext_vector_type(4)));
typedef float    f32x4 __attribute__((ext_vector_type(4)));

// ---- A-fragment arena (f16 units). Frag = 64 lanes x 8 f16 = 512.
// Bias columns folded into zero K-slots:
//   step1 k=72 -> lu_bias ; step2 k=44 -> b0 ; gate k=44 -> cb ; encW1 k=44 -> enc_b1
#define PB    37376
#define S1O   0                // 15 frags
#define S2O   7680             // 8 frags
#define RBO   11776            // per i stride 10240: l1 8, l2 8, gate 4
#define RB_L1 0
#define RB_L2 4096
#define RB_GW 8192
#define S4O   32256            // 10 frags
#define E1O   (16 * PB)
#define E2O   (E1O + 2048)

#define XOFF  (64 * 104)       // second-tile offset in ActX
#define HOFF  (64 * 72)        // second-tile offset in ActH/ActT

__device__ inline half4 pk4(f32x4 v) {
    half4 h; h[0] = (_Float16)v[0]; h[1] = (_Float16)v[1];
    h[2] = (_Float16)v[2]; h[3] = (_Float16)v[3]; return h;
}
__device__ inline half4 pk4r(f32x4 v) {
    half4 h;
    h[0] = (_Float16)fmaxf(v[0], 0.f); h[1] = (_Float16)fmaxf(v[1], 0.f);
    h[2] = (_Float16)fmaxf(v[2], 0.f); h[3] = (_Float16)fmaxf(v[3], 0.f);
    return h;
}
__device__ inline float sigf(float x) {
    return __fdividef(1.f, 1.f + __expf(-x));
}
__device__ inline f32x4 MF(half8 a, half8 b, f32x4 c) {
    return __builtin_amdgcn_mfma_f32_16x16x32_f16(a, b, c, 0, 0, 0);
}

// ---------------------------------------------------------------------------
// Merged prep: wgs 0..79 = LU compose (blk, mtile); wgs 80.. = static weights.
// ---------------------------------------------------------------------------
__global__ __launch_bounds__(256) void prep_all(
    const float* __restrict__ lu_lower, const float* __restrict__ lu_upper,
    const float* __restrict__ lu_diag,  const float* __restrict__ lu_bias,
    const float* __restrict__ cn_W0, const float* __restrict__ cn_ctxW,
    const float* __restrict__ cn_l1W, const float* __restrict__ cn_l2W,
    const float* __restrict__ cn_Wf, const float* __restrict__ enc_W1,
    const float* __restrict__ enc_W2,
    const float* __restrict__ cn_b0, const float* __restrict__ cn_ctxb,
    const float* __restrict__ enc_b1,
    _Float16* __restrict__ AR, float* __restrict__ wsLd)
{
    const int tid = threadIdx.x;
    __shared__ float Ls[DD][DD + 1];
    __shared__ float Us[DD][DD + 1];
    __shared__ float diag[DD], ldp[DD];

    if (blockIdx.x < 80) {
        const int wg  = blockIdx.x;
        const int blk = wg / 5, mt = wg % 5;
        const float* L = lu_lower + blk * DD * DD;
        const float* U = lu_upper + blk * DD * DD;
        for (int e = tid; e < DD * DD; e += 256) {
            Ls[e / DD][e % DD] = L[e];
            Us[e / DD][e % DD] = U[e];
        }
        if (tid < DD) {
            float v  = lu_diag[blk * DD + tid];
            float sp = log1pf(expf(v)) + 0.001f;
            diag[tid] = sp; ldp[tid] = logf(sp);
        }
        __syncthreads();
        if (mt == 0 && tid == 0) {
            float s = 0.f;
            for (int i = 0; i < DD; ++i) s += ldp[i];
            wsLd[blk] = s;
        }
        if (tid < 192) {
            const int kt = tid >> 6, lane = tid & 63;
            const int m  = mt * 16 + (lane & 15);
            const int k0 = kt * 32 + (lane >> 4) * 8;
            float acc[8] = {0.f,0.f,0.f,0.f,0.f,0.f,0.f,0.f};
            if (m < DD) {
                for (int kk = 0; kk < m; ++kk) {
                    const float a = Ls[m][kk];
                    #pragma unroll
                    for (int j = 0; j < 8; ++j) {
                        const int k = k0 + j;
                        if (k < DD && kk < k) acc[j] = fmaf(a, Us[kk][k], acc[j]);
                    }
                }
                #pragma unroll
                for (int j = 0; j < 8; ++j) {
                    const int k = k0 + j;
                    if (k < DD) {
                        if      (m < k)  acc[j] += Us[m][k];
                        else if (m == k) acc[j] += diag[k];
                        else             acc[j] += Ls[m][k] * diag[k];
                    }
                }
            }
            half8 hv;
            #pragma unroll
            for (int j = 0; j < 8; ++j) {
                const int k = k0 + j;
                float v = 0.f;
                if (m < DD) {
                    if      (k < DD)  v = acc[j];
                    else if (k == DD) v = lu_bias[blk * DD + m];
                }
                hv[j] = (_Float16)v;
            }
            *(half8*)(AR + (size_t)blk * PB + S1O + (size_t)(mt * 3 + kt) * 512
                      + (size_t)lane * 8) = hv;
        }
        return;
    }

    // ---- static-weight branch ----
    int gid = (blockIdx.x - 80) * 256 + tid;
    int fid = gid >> 6, lane = gid & 63;
    if (fid >= 950) return;
    const int mrow = lane & 15, kcol0 = (lane >> 4) * 8;

    const float* src = nullptr; const float* bias = nullptr;
    size_t dst = 0;
    int m = 0, kbase = 0, rows = 64, kv_lo = 0, kv_hi = 64, sstr = 64, ksub = 0, kbias = -1;

    if (fid < 128) {
        int blk = fid >> 3, f = fid & 7;
        int mt = f >> 1, kt = f & 1;
        src = cn_W0 + (size_t)blk * 64 * 44; sstr = 44;
        dst = (size_t)blk * PB + S2O + (size_t)f * 512;
        m = mt * 16 + mrow; kbase = kt * 32 + kcol0; kv_hi = 44;
        bias = cn_b0 + (size_t)blk * 64; kbias = 44;
    } else if (fid < 384) {
        int id = fid - 128, bi = id >> 3, f = id & 7;
        int mt = f >> 1, kt = f & 1;
        src = cn_l1W + (size_t)bi * 4096;
        dst = (size_t)(bi >> 1) * PB + RBO + (size_t)(bi & 1) * 10240 + RB_L1 + (size_t)f * 512;
        m = mt * 16 + mrow; kbase = kt * 32 + kcol0;
    } else if (fid < 640) {
        int id = fid - 384, bi = id >> 3, f = id & 7;
        int mt = f >> 1, kt = f & 1;
        src = cn_l2W + (size_t)bi * 4096;
        dst = (size_t)(bi >> 1) * PB + RBO + (size_t)(bi & 1) * 10240 + RB_L2 + (size_t)f * 512;
        m = mt * 16 + mrow; kbase = kt * 32 + kcol0;
    } else if (fid < 768) {
        int id = fid - 640, bi = id >> 2, mt = id & 3;
        src = cn_ctxW + (size_t)bi * 512; sstr = 8;
        dst = (size_t)(bi >> 1) * PB + RBO + (size_t)(bi & 1) * 10240 + RB_GW + (size_t)mt * 512;
        m = mt * 16 + mrow; kbase = 32 + kcol0; kv_lo = 36; kv_hi = 44; ksub = 36;
        bias = cn_ctxb + (size_t)bi * 64; kbias = 44;
    } else if (fid < 928) {
        int id = fid - 768, blk = id / 10, f = id % 10;
        int mt = f >> 1, kt = f & 1;
        src = cn_Wf + (size_t)blk * 4608;
        dst = (size_t)blk * PB + S4O + (size_t)f * 512;
        m = mt * 16 + mrow; kbase = kt * 32 + kcol0; rows = 72;
    } else if (fid < 932) {
        int mt = fid - 928;
        src = enc_W1; sstr = 8;
        dst = E1O + (size_t)mt * 512;
        m = mt * 16 + mrow; kbase = 32 + kcol0; kv_lo = 36; kv_hi = 44; ksub = 36;
        bias = enc_b1; kbias = 44;
    } else {
        int id = fid - 932, mt = id >> 1, kt = id & 1;
        src = enc_W2;
        dst = E2O + (size_t)id * 512;
        m = mt * 16 + mrow; kbase = kt * 32 + kcol0; rows = 144;
    }
    half8 hv;
    #pragma unroll
    for (int j = 0; j < 8; ++j) {
        const int k = kbase + j;
        float v = 0.f;
        if (m < rows) {
            if (k >= kv_lo && k < kv_hi) v = src[(size_t)m * sstr + (k - ksub)];
            else if (k == kbias)         v = bias[m];
        }
        hv[j] = (_Float16)v;
    }
    *(half8*)(AR + dst + (size_t)lane * 8) = hv;
}

// ---------------------------------------------------------------------------
// Flow kernel: DUAL B-tile per wave (32 batch rows). A-frag loads amortized 2x.
// ---------------------------------------------------------------------------
#define LDH8(off) (*(const half8*)(AR + (size_t)(off) + lane8))
#define MFMA_A(acc, off, bf) acc = MF(LDH8(off), bf, acc)

__global__ __launch_bounds__(256, 2) void flow_kernel(
    const float* __restrict__ traj,
    const float* __restrict__ start,
    const float* __restrict__ goal,
    const float* __restrict__ cn_l1b,
    const float* __restrict__ cn_l2b,
    const float* __restrict__ cn_bf,
    const float* __restrict__ enc_b2,
    const _Float16* __restrict__ AR,
    const float* __restrict__ wsLd,
    float* __restrict__ out, int B)
{
    __shared__ __align__(16) _Float16 ActX[128 * 104];  // x(0..71) | 1@72 | 0
    __shared__ __align__(16) _Float16 ActH[128 * 72];   // h_id | ctx(36..43) | 1@44 | 0
    __shared__ __align__(16) _Float16 ActT[128 * 72];

    const int tid  = threadIdx.x;
    const int lane = tid & 63;
    const int w    = __builtin_amdgcn_readfirstlane(tid >> 6);
    const int n    = lane & 15, lg = lane >> 4;
    const int bg0  = blockIdx.x * 128;
    const size_t lane8 = (size_t)lane * 8;

    // ---- init: stage 128 batch rows of x and ctx into LDS ----
    #pragma unroll
    for (int r = 0; r < 18; ++r) {                      // 128*36 float2
        int e = tid + 256 * r;
        int b = e / 36, p = e % 36;
        float2 v = *(const float2*)(traj + (size_t)(bg0 + b) * DD + 2 * p);
        ActX[b * 104 + 2 * p]     = (_Float16)v.x;
        ActX[b * 104 + 2 * p + 1] = (_Float16)v.y;
    }
    #pragma unroll
    for (int r = 0; r < 16; ++r) {                      // cols 72..103
        int e = tid + 256 * r;
        int b = e / 32, c = 72 + e % 32;
        ActX[b * 104 + c] = (c == 72) ? (_Float16)1.f : (_Float16)0.f;
    }
    #pragma unroll
    for (int r = 0; r < 2; ++r) {                       // ctx: 128 rows x 4 pairs
        int e = tid + 256 * r;
        int b = e >> 2, cp = e & 3;
        const float* s = (cp < 2) ? (start + (size_t)(bg0 + b) * 4 + 2 * cp)
                                  : (goal  + (size_t)(bg0 + b) * 4 + 2 * (cp - 2));
        ActH[b * 72 + 36 + 2 * cp]     = (_Float16)s[0];
        ActH[b * 72 + 36 + 2 * cp + 1] = (_Float16)s[1];
    }
    #pragma unroll
    for (int r = 0; r < 14; ++r) {                      // cols 44..71
        int e = tid + 256 * r;
        int b = e / 28, c = 44 + e % 28;
        ActH[b * 72 + c] = (c == 44) ? (_Float16)1.f : (_Float16)0.f;
    }

    // prologue prefetch: block 0 step1 frags for mtiles 0,1
    half8 s1p0 = LDH8(S1O + 0 * 512), s1p1 = LDH8(S1O + 1 * 512),
          s1p2 = LDH8(S1O + 2 * 512), s1p3 = LDH8(S1O + 3 * 512),
          s1p4 = LDH8(S1O + 4 * 512), s1p5 = LDH8(S1O + 5 * 512);

    __syncthreads();

    const int bx = (16 * w + n) * 104;   // tile0; tile1 = +XOFF
    const int bh = (16 * w + n) * 72;    // tile0; tile1 = +HOFF

    float ldac[2] = {0.f, 0.f};
    const f32x4 z4 = {0.f, 0.f, 0.f, 0.f};

    #pragma unroll 1
    for (int blk = 0; blk < NBLK; ++blk) {
        __syncthreads();
        const size_t B0 = (size_t)blk * PB;

        // ---- step1: y = W @ x (+bias col); frags loaded once, used twice ----
        half8 f6  = LDH8(B0 + S1O + 6 * 512),  f7  = LDH8(B0 + S1O + 7 * 512),
              f8  = LDH8(B0 + S1O + 8 * 512),  f9  = LDH8(B0 + S1O + 9 * 512),
              f10 = LDH8(B0 + S1O + 10 * 512), f11 = LDH8(B0 + S1O + 11 * 512),
              f12 = LDH8(B0 + S1O + 12 * 512), f13 = LDH8(B0 + S1O + 13 * 512),
              f14 = LDH8(B0 + S1O + 14 * 512);
        f32x4 y[2][5];
        #pragma unroll
        for (int u = 0; u < 2; ++u) {
            const int ox = bx + u * XOFF;
            half8 b0v = *(const half8*)&ActX[ox + 0  + lg * 8];
            half8 b1v = *(const half8*)&ActX[ox + 32 + lg * 8];
            half8 b2v = *(const half8*)&ActX[ox + 64 + lg * 8];
            y[u][0] = MF(s1p2, b2v, MF(s1p1, b1v, MF(s1p0, b0v, z4)));
            y[u][1] = MF(s1p5, b2v, MF(s1p4, b1v, MF(s1p3, b0v, z4)));
            y[u][2] = MF(f8,  b2v, MF(f7,  b1v, MF(f6,  b0v, z4)));
            y[u][3] = MF(f11, b2v, MF(f10, b1v, MF(f9,  b0v, z4)));
            y[u][4] = MF(f14, b2v, MF(f13, b1v, MF(f12, b0v, z4)));
        }

        // ---- step2 ----
        half8 g0 = LDH8(B0 + S2O + 0 * 512), g1 = LDH8(B0 + S2O + 1 * 512),
              g2 = LDH8(B0 + S2O + 2 * 512), g3 = LDH8(B0 + S2O + 3 * 512),
              g4 = LDH8(B0 + S2O + 4 * 512), g5 = LDH8(B0 + S2O + 5 * 512),
              g6 = LDH8(B0 + S2O + 6 * 512), g7 = LDH8(B0 + S2O + 7 * 512);
        #pragma unroll
        for (int u = 0; u < 2; ++u) {
            const int ox = bx + u * XOFF, oh = bh + u * HOFF;
            if (lg >= 1) { half4 hv = pk4(y[u][2]); int m0 = 32 + lg * 4;
                *(half4*)&ActX[ox + m0] = hv; *(half4*)&ActH[oh + m0 - 36] = hv; }
            {            half4 hv = pk4(y[u][3]); int m0 = 48 + lg * 4;
                *(half4*)&ActX[ox + m0] = hv; *(half4*)&ActH[oh + m0 - 36] = hv; }
            if (lg < 2) { half4 hv = pk4(y[u][4]); int m0 = 64 + lg * 4;
                *(half4*)&ActX[ox + m0] = hv; *(half4*)&ActH[oh + m0 - 36] = hv; }
        }
        half8 bhv0[2], bhv1[2];
        f32x4 t[2][4];
        #pragma unroll
        for (int u = 0; u < 2; ++u) {
            const int oh = bh + u * HOFF;
            bhv0[u] = *(const half8*)&ActH[oh + 0  + lg * 8];
            bhv1[u] = *(const half8*)&ActH[oh + 32 + lg * 8];
            t[u][0] = MF(g1, bhv1[u], MF(g0, bhv0[u], z4));
            t[u][1] = MF(g3, bhv1[u], MF(g2, bhv0[u], z4));
            t[u][2] = MF(g5, bhv1[u], MF(g4, bhv0[u], z4));
            t[u][3] = MF(g7, bhv1[u], MF(g6, bhv0[u], z4));
        }

        // ---- two residual blocks ----
        #pragma unroll
        for (int i = 0; i < 2; ++i) {
            const size_t RB = B0 + RBO + (size_t)i * 10240;
            half8 r0 = LDH8(RB + RB_L1 + 0 * 512), r1 = LDH8(RB + RB_L1 + 1 * 512),
                  r2 = LDH8(RB + RB_L1 + 2 * 512), r3 = LDH8(RB + RB_L1 + 3 * 512),
                  r4 = LDH8(RB + RB_L1 + 4 * 512), r5 = LDH8(RB + RB_L1 + 5 * 512),
                  r6 = LDH8(RB + RB_L1 + 6 * 512), r7 = LDH8(RB + RB_L1 + 7 * 512);
            #pragma unroll
            for (int u = 0; u < 2; ++u) {
                const int ot = bh + u * HOFF;
                #pragma unroll
                for (int mt = 0; mt < 4; ++mt)
                    *(half4*)&ActT[ot + mt * 16 + lg * 4] = pk4r(t[u][mt]);
            }
            f32x4 a1[2][4];
            #pragma unroll
            for (int u = 0; u < 2; ++u) {
                const int ot = bh + u * HOFF;
                half8 c0 = *(const half8*)&ActT[ot + 0  + lg * 8];
                half8 c1 = *(const half8*)&ActT[ot + 32 + lg * 8];
                a1[u][0] = MF(r1, c1, MF(r0, c0, z4));
                a1[u][1] = MF(r3, c1, MF(r2, c0, z4));
                a1[u][2] = MF(r5, c1, MF(r4, c0, z4));
                a1[u][3] = MF(r7, c1, MF(r6, c0, z4));
            }
            half8 q0 = LDH8(RB + RB_L2 + 0 * 512), q1 = LDH8(RB + RB_L2 + 1 * 512),
                  q2 = LDH8(RB + RB_L2 + 2 * 512), q3 = LDH8(RB + RB_L2 + 3 * 512),
                  q4 = LDH8(RB + RB_L2 + 4 * 512), q5 = LDH8(RB + RB_L2 + 5 * 512),
                  q6 = LDH8(RB + RB_L2 + 6 * 512), q7 = LDH8(RB + RB_L2 + 7 * 512);
            half8 w0 = LDH8(RB + RB_GW + 0 * 512), w1 = LDH8(RB + RB_GW + 1 * 512),
                  w2 = LDH8(RB + RB_GW + 2 * 512), w3 = LDH8(RB + RB_GW + 3 * 512);
            float4 bb1[4];
            #pragma unroll
            for (int mt = 0; mt < 4; ++mt)
                bb1[mt] = *(const float4*)(cn_l1b + (blk * 2 + i) * 64 + mt * 16 + lg * 4);
            #pragma unroll
            for (int u = 0; u < 2; ++u) {
                const int ot = bh + u * HOFF;
                #pragma unroll
                for (int mt = 0; mt < 4; ++mt) {
                    a1[u][mt][0] += bb1[mt].x; a1[u][mt][1] += bb1[mt].y;
                    a1[u][mt][2] += bb1[mt].z; a1[u][mt][3] += bb1[mt].w;
                    *(half4*)&ActT[ot + mt * 16 + lg * 4] = pk4r(a1[u][mt]);
                }
            }
            float4 bb2[4];
            #pragma unroll
            for (int mt = 0; mt < 4; ++mt)
                bb2[mt] = *(const float4*)(cn_l2b + (blk * 2 + i) * 64 + mt * 16 + lg * 4);
            #pragma unroll
            for (int u = 0; u < 2; ++u) {
                const int ot = bh + u * HOFF;
                half8 c0 = *(const half8*)&ActT[ot + 0  + lg * 8];
                half8 c1 = *(const half8*)&ActT[ot + 32 + lg * 8];
                f32x4 a2[4], gg[4];
                a2[0] = MF(q1, c1, MF(q0, c0, z4));
                a2[1] = MF(q3, c1, MF(q2, c0, z4));
                a2[2] = MF(q5, c1, MF(q4, c0, z4));
                a2[3] = MF(q7, c1, MF(q6, c0, z4));
                gg[0] = MF(w0, bhv1[u], z4); gg[1] = MF(w1, bhv1[u], z4);
                gg[2] = MF(w2, bhv1[u], z4); gg[3] = MF(w3, bhv1[u], z4);
                #pragma unroll
                for (int mt = 0; mt < 4; ++mt) {
                    #pragma unroll
                    for (int r = 0; r < 4; ++r) {
                        float av = a2[mt][r] + ((const float*)&bb2[mt])[r];
                        t[u][mt][r] = fmaf(av, sigf(gg[mt][r]), t[u][mt][r]);
                    }
                }
            }
        }

        // ---- step4: params = Wf @ t + bf ----
        half8 h0 = LDH8(B0 + S4O + 0 * 512), h1 = LDH8(B0 + S4O + 1 * 512),
              h2 = LDH8(B0 + S4O + 2 * 512), h3 = LDH8(B0 + S4O + 3 * 512),
              h4 = LDH8(B0 + S4O + 4 * 512), h5 = LDH8(B0 + S4O + 5 * 512),
              h6 = LDH8(B0 + S4O + 6 * 512), h7 = LDH8(B0 + S4O + 7 * 512),
              h8 = LDH8(B0 + S4O + 8 * 512), h9 = LDH8(B0 + S4O + 9 * 512);
        #pragma unroll
        for (int u = 0; u < 2; ++u) {
            const int ot = bh + u * HOFF;
            #pragma unroll
            for (int mt = 0; mt < 4; ++mt)
                *(half4*)&ActT[ot + mt * 16 + lg * 4] = pk4(t[u][mt]);
        }
        float4 bfv[5];
        #pragma unroll
        for (int mt = 0; mt < 5; ++mt) {
            int bm = mt * 16 + lg * 4; if (bm > 68) bm = 68;
            bfv[mt] = *(const float4*)(cn_bf + blk * DD + bm);
        }
        f32x4 p[2][5];
        #pragma unroll
        for (int u = 0; u < 2; ++u) {
            const int ot = bh + u * HOFF;
            half8 c0 = *(const half8*)&ActT[ot + 0  + lg * 8];
            half8 c1 = *(const half8*)&ActT[ot + 32 + lg * 8];
            p[u][0] = MF(h1, c1, MF(h0, c0, z4));
            p[u][1] = MF(h3, c1, MF(h2, c0, z4));
            p[u][2] = MF(h5, c1, MF(h4, c0, z4));
            p[u][3] = MF(h7, c1, MF(h6, c0, z4));
            p[u][4] = MF(h9, c1, MF(h8, c0, z4));
            #pragma unroll
            for (int mt = 0; mt < 5; ++mt) {
                p[u][mt][0] += bfv[mt].x; p[u][mt][1] += bfv[mt].y;
                p[u][mt][2] += bfv[mt].z; p[u][mt][3] += bfv[mt].w;
            }
        }

        // ---- cross-block prefetch: next block's step1 mtiles 0,1 ----
        {
            const size_t Bn = (size_t)(blk < NBLK - 1 ? blk + 1 : blk) * PB;
            s1p0 = LDH8(Bn + S1O + 0 * 512); s1p1 = LDH8(Bn + S1O + 1 * 512);
            s1p2 = LDH8(Bn + S1O + 2 * 512); s1p3 = LDH8(Bn + S1O + 3 * 512);
            s1p4 = LDH8(Bn + S1O + 4 * 512); s1p5 = LDH8(Bn + S1O + 5 * 512);
        }

        // ---- scale rows + combine, per tile ----
        #pragma unroll
        for (int u = 0; u < 2; ++u) {
            const int ot = bh + u * HOFF, ox = bx + u * XOFF;
            if (lg >= 1) {
                f32x4 s;
                #pragma unroll
                for (int r = 0; r < 4; ++r) {
                    s[r] = sigf(p[u][2][r] + 2.f) + 0.001f;
                    ldac[u] += __logf(s[r]);
                }
                *(half4*)&ActT[ot + (32 + lg * 4) - 36] = pk4(s);
            }
            {
                f32x4 s;
                #pragma unroll
                for (int r = 0; r < 4; ++r) {
                    s[r] = sigf(p[u][3][r] + 2.f) + 0.001f;
                    ldac[u] += __logf(s[r]);
                }
                *(half4*)&ActT[ot + (48 + lg * 4) - 36] = pk4(s);
            }
            if (lg < 2) {
                f32x4 s;
                #pragma unroll
                for (int r = 0; r < 4; ++r) {
                    s[r] = sigf(p[u][4][r] + 2.f) + 0.001f;
                    ldac[u] += __logf(s[r]);
                }
                *(half4*)&ActT[ot + (64 + lg * 4) - 36] = pk4(s);
            }
            {
                half4 sv = *(const half4*)&ActT[ot + lg * 4];
                f32x4 xn;
                #pragma unroll
                for (int r = 0; r < 4; ++r) xn[r] = fmaf(y[u][0][r], (float)sv[r], p[u][0][r]);
                *(half4*)&ActX[ox + lg * 4] = pk4(xn);
            }
            {
                half4 sv = *(const half4*)&ActT[ot + 16 + lg * 4];
                f32x4 xn;
                #pragma unroll
                for (int r = 0; r < 4; ++r) xn[r] = fmaf(y[u][1][r], (float)sv[r], p[u][1][r]);
                *(half4*)&ActX[ox + 16 + lg * 4] = pk4(xn);
            }
            if (lg == 0) {
                half4 sv = *(const half4*)&ActT[ot + 32];
                f32x4 xn;
                #pragma unroll
                for (int r = 0; r < 4; ++r) xn[r] = fmaf(y[u][2][r], (float)sv[r], p[u][2][r]);
                *(half4*)&ActX[ox + 32] = pk4(xn);
            }
        }
    }

    // ---- encoder head, per tile (E-frag loads via macro; L1-hot on 2nd pass) ----
    float qp[2] = {0.f, 0.f}, slsp[2] = {0.f, 0.f};
    #pragma unroll
    for (int u = 0; u < 2; ++u) {
        const int ot = bh + u * HOFF, ox = bx + u * XOFF, oh = bh + u * HOFF;
        half8 bh1u = *(const half8*)&ActH[oh + 32 + lg * 8];
        #pragma unroll
        for (int mt = 0; mt < 4; ++mt) {
            f32x4 a = z4;
            MFMA_A(a, E1O + mt * 512, bh1u);
            *(half4*)&ActT[ot + mt * 16 + lg * 4] = pk4r(a);
        }
        half8 c0 = *(const half8*)&ActT[ot + 0  + lg * 8];
        half8 c1 = *(const half8*)&ActT[ot + 32 + lg * 8];
        f32x4 me[9];
        #pragma unroll
        for (int mt = 0; mt < 9; ++mt) {
            f32x4 a = z4;
            MFMA_A(a, E2O + (mt * 2 + 0) * 512, c0);
            MFMA_A(a, E2O + (mt * 2 + 1) * 512, c1);
            const float4 bb = *(const float4*)(enc_b2 + mt * 16 + lg * 4);
            me[mt][0] = a[0] + bb.x; me[mt][1] = a[1] + bb.y;
            me[mt][2] = a[2] + bb.z; me[mt][3] = a[3] + bb.w;
        }
        if (lg >= 2) {
            #pragma unroll
            for (int r = 0; r < 4; ++r) slsp[u] += me[4][r];
            *(half4*)&ActT[ot + lg * 4 - 8] = pk4(me[4]);
        }
        #pragma unroll
        for (int mt = 5; mt < 9; ++mt) {
            #pragma unroll
            for (int r = 0; r < 4; ++r) slsp[u] += me[mt][r];
            *(half4*)&ActT[ot + (mt * 16 + lg * 4) - 72] = pk4(me[mt]);
        }
        #pragma unroll
        for (int mt = 0; mt < 4; ++mt) {
            int m0 = mt * 16 + lg * 4;
            half4 xv = *(const half4*)&ActX[ox + m0];
            half4 lv = *(const half4*)&ActT[ot + m0];
            #pragma unroll
            for (int r = 0; r < 4; ++r) {
                float zz = ((float)xv[r] - me[mt][r]) * __expf(-(float)lv[r]);
                qp[u] = fmaf(zz, zz, qp[u]);
            }
        }
        if (lg < 2) {
            int m0 = 64 + lg * 4;
            half4 xv = *(const half4*)&ActX[ox + m0];
            half4 lv = *(const half4*)&ActT[ot + m0];
            #pragma unroll
            for (int r = 0; r < 4; ++r) {
                float zz = ((float)xv[r] - me[4][r]) * __expf(-(float)lv[r]);
                qp[u] = fmaf(zz, zz, qp[u]);
            }
        }
    }

    float ldsum = 0.f;
    #pragma unroll
    for (int k = 0; k < NBLK; ++k) ldsum += wsLd[k];
    #pragma unroll
    for (int u = 0; u < 2; ++u) {
        float q = qp[u], s = slsp[u], l = ldac[u];
        q += __shfl_xor(q, 16); q += __shfl_xor(q, 32);
        s += __shfl_xor(s, 16); s += __shfl_xor(s, 32);
        l += __shfl_xor(l, 16); l += __shfl_xor(l, 32);
        if (lane < 16) {
            // 0.5 * 72 * log(2*pi) = 66.16357439
            out[bg0 + u * 64 + 16 * w + lane] = -0.5f * q - s - 66.1635744f + l + ldsum;
        }
    }
}

// ---------------------------------------------------------------------------
extern "C" void kernel_launch(void* const* d_in, const int* in_sizes, int n_in,
                              void* d_out, int out_size, void* d_ws, size_t ws_size,
                              hipStream_t stream) {
    const float* traj     = (const float*)d_in[0];
    const float* start    = (const float*)d_in[1];
    const float* goal     = (const float*)d_in[2];
    const float* lu_lower = (const float*)d_in[3];
    const float* lu_upper = (const float*)d_in[4];
    const float* lu_diag  = (const float*)d_in[5];
    const float* lu_bias  = (const float*)d_in[6];
    const float* cn_W0    = (const float*)d_in[7];
    const float* cn_b0    = (const float*)d_in[8];
    const float* cn_ctxW  = (const float*)d_in[9];
    const float* cn_ctxb  = (const float*)d_in[10];
    const float* cn_l1W   = (const float*)d_in[11];
    const float* cn_l1b   = (const float*)d_in[12];
    const float* cn_l2W   = (const float*)d_in[13];
    const float* cn_l2b   = (const float*)d_in[14];
    const float* cn_Wf    = (const float*)d_in[15];
    const float* cn_bf    = (const float*)d_in[16];
    const float* enc_W1   = (const float*)d_in[17];
    const float* enc_b1   = (const float*)d_in[18];
    const float* enc_W2   = (const float*)d_in[19];
    const float* enc_b2   = (const float*)d_in[20];

    float* outp = (float*)d_out;
    const int B = in_sizes[0] / DD;

    float*     wsLd = (float*)d_ws;
    _Float16*  AR   = (_Float16*)((char*)d_ws + 256);

    hipLaunchKernelGGL(prep_all, dim3(80 + 238), dim3(256), 0, stream,
                       lu_lower, lu_upper, lu_diag, lu_bias,
                       cn_W0, cn_ctxW, cn_l1W, cn_l2W, cn_Wf, enc_W1, enc_W2,
                       cn_b0, cn_ctxb, enc_b1, AR, wsLd);

    hipLaunchKernelGGL(flow_kernel, dim3(B / 128), dim3(256), 0, stream,
                       traj, start, goal,
                       cn_l1b, cn_l2b, cn_bf, enc_b2,
                       AR, wsLd, outp, B);
}